// Round 7
// baseline (27.081 us; speedup 1.0000x reference)
//
#include <hip/hip_runtime.h>
#include <math.h>

// Problem geometry (fixed by the reference): probability [64, 2, 512, 512] fp32.
constexpr int B       = 64;
constexpr int HW      = 512 * 512;        // pixels per (batch, channel)
constexpr int CHUNKS  = 32;               // blocks per batch -> 2048 blocks total
constexpr int PIX     = HW / CHUNKS;      // 8192 pixels per block
constexpr int THREADS = 512;              // R7: 512 thr -> 32 floats/thread ->
constexpr int NBLK    = B * CHUNKS;       //     ~50 VGPR -> 8 waves/SIMD resident
constexpr int ITER    = PIX / 4 / THREADS; // 4 float4 pairs per thread

// Kernel 1: per-block partial sums of sigmoid(x1 - x0) = softmax(axis=1)[ch 1].
// 512 threads x 32 floats: low VGPR footprint for full occupancy (32 waves/CU),
// loads staged first so 8 float4 loads are in flight per wave.
__global__ __launch_bounds__(THREADS)
void lb_partials(const float* __restrict__ prob, float* __restrict__ partials) {
    const int blk = blockIdx.x;
    const int b   = blk >> 5;             // blk / CHUNKS
    const int c   = blk & (CHUNKS - 1);   // blk % CHUNKS

    const float4* __restrict__ x0 =
        reinterpret_cast<const float4*>(prob + (size_t)b * 2 * HW + (size_t)c * PIX);
    const float4* __restrict__ x1 =
        reinterpret_cast<const float4*>(prob + (size_t)b * 2 * HW + HW + (size_t)c * PIX);

    float4 a[ITER], d[ITER];
    #pragma unroll
    for (int it = 0; it < ITER; ++it) {
        const int i = it * THREADS + threadIdx.x;
        a[it] = x0[i];
        d[it] = x1[i];
    }

    float acc = 0.f;
    #pragma unroll
    for (int it = 0; it < ITER; ++it) {
        // sigmoid(d-a) = 1/(1+exp(a-d)); fast exp + rcp (abs threshold 312 — huge slack)
        acc += __builtin_amdgcn_rcpf(1.f + __expf(a[it].x - d[it].x));
        acc += __builtin_amdgcn_rcpf(1.f + __expf(a[it].y - d[it].y));
        acc += __builtin_amdgcn_rcpf(1.f + __expf(a[it].z - d[it].z));
        acc += __builtin_amdgcn_rcpf(1.f + __expf(a[it].w - d[it].w));
    }

    // wave64 reduction, then cross-wave via LDS
    #pragma unroll
    for (int off = 32; off > 0; off >>= 1)
        acc += __shfl_down(acc, off, 64);

    __shared__ float sdata[THREADS / 64];
    const int lane = threadIdx.x & 63;
    const int wid  = threadIdx.x >> 6;
    if (lane == 0) sdata[wid] = acc;
    __syncthreads();
    if (threadIdx.x == 0) {
        float s = 0.f;
        #pragma unroll
        for (int w = 0; w < THREADS / 64; ++w) s += sdata[w];
        partials[blk] = s;
    }
}

// Kernel 2: ONE wave. Lane b = batch b: 8 independent float4 loads (all in
// flight -> single memory round-trip), double-precision sum, in-wave finale.
__global__ __launch_bounds__(64)
void lb_final(const float* __restrict__ partials, float* __restrict__ out) {
    const int b = threadIdx.x;            // 0..63 == batch index
    const float4* __restrict__ p4 =
        reinterpret_cast<const float4*>(partials + b * CHUNKS);

    float4 v[8];
    #pragma unroll
    for (int k = 0; k < 8; ++k) v[k] = p4[k];   // 8 loads issued back-to-back

    double s = 0.0;
    #pragma unroll
    for (int k = 0; k < 8; ++k) {
        s += (double)v[k].x;
        s += (double)v[k].y;
        s += (double)v[k].z;
        s += (double)v[k].w;
    }

    const double LOW  = 131050.0;
    const double HIGH = 131100.0;

    // low_vec_sum = sum over the whole batch of (s - LOW)^2
    double dl  = s - LOW;
    double lvs = dl * dl;
    #pragma unroll
    for (int off = 32; off > 0; off >>= 1) lvs += __shfl_xor(lvs, off, 64);

    // Faithful reproduction of the reference's branchy contributions.
    double contrib, count;
    if (s >= HIGH)      { double dd = s - HIGH; contrib = dd * dd; count = 1.0; }
    else if (s <= LOW)  { contrib = lvs;                           count = (double)B; }
    else                { contrib = 0.0;                           count = 1.0; }

    double cs = contrib, cn = count;
    #pragma unroll
    for (int off = 32; off > 0; off >>= 1) {
        cs += __shfl_xor(cs, off, 64);
        cn += __shfl_xor(cn, off, 64);
    }
    if (b == 0) out[0] = (float)(cs / cn);
}

extern "C" void kernel_launch(void* const* d_in, const int* in_sizes, int n_in,
                              void* d_out, int out_size, void* d_ws, size_t ws_size,
                              hipStream_t stream) {
    const float* prob     = (const float*)d_in[0];
    float*       out      = (float*)d_out;
    float*       partials = (float*)d_ws;   // 2048 floats, written before read

    lb_partials<<<NBLK, THREADS, 0, stream>>>(prob, partials);
    lb_final<<<1, 64, 0, stream>>>(partials, out);
}